// Round 8
// baseline (282.207 us; speedup 1.0000x reference)
//
#include <hip/hip_runtime.h>
#include <math.h>

#define NEGF (-1.0e9f)
#define NB 4   // batches per block

typedef __attribute__((ext_vector_type(8))) short short8;
typedef __attribute__((ext_vector_type(4))) float f32x4;

static __device__ __forceinline__ unsigned short bf16_rne(float f) {
    unsigned int u = __float_as_uint(f);
    u += 0x7FFFu + ((u >> 16) & 1u);
    return (unsigned short)(u >> 16);
}

// packed 2x f32 -> 2x bf16 (RNE), D[15:0]=cvt(S0), D[31:16]=cvt(S1)
static __device__ __forceinline__ unsigned cvt_pk_bf16(float a, float b) {
    unsigned r;
    asm("v_cvt_pk_bf16_f32 %0, %1, %2" : "=v"(r) : "v"(a), "v"(b));
    return r;
}

// Kernel A: segment boundaries from sorted batch_index.
__global__ void seg_bounds_kernel(const int* __restrict__ bi, int M, int B,
                                  int* __restrict__ seg) {
    int m = blockIdx.x * blockDim.x + threadIdx.x;
    if (m >= M) return;
    int cur = bi[m];
    if (m == 0) {
        for (int b = 0; b <= cur; ++b) seg[b] = 0;
    } else {
        int prev = bi[m - 1];
        for (int b = prev + 1; b <= cur; ++b) seg[b] = m;
    }
    if (m == M - 1) {
        for (int b = cur + 1; b <= B; ++b) seg[b] = M;
    }
}

// Kernel P: split w2 [64 k][128 col] into hi/lo bf16 in per-lane MFMA
// B-fragment order. ushort layout: [cg 8][ks 2][p 2][slot 64][e 8],
// slot = kg*16+lane16, value = bf16split_p(w2[ks*32+kg*8+e][cg*16+lane16]).
__global__ void prep_w2_kernel(const float* __restrict__ w2,
                               unsigned short* __restrict__ wf) {
    int t = blockIdx.x * blockDim.x + threadIdx.x;   // 0..8191
    if (t >= 8192) return;
    int e = t & 7, slot = (t >> 3) & 63, ks = (t >> 9) & 1, cg = t >> 10;
    int lane16 = slot & 15, kg = slot >> 4;
    int k = ks * 32 + kg * 8 + e;
    int col = cg * 16 + lane16;
    float w = w2[k * 128 + col];
    unsigned ub = __float_as_uint(w);
    unsigned short hi = (unsigned short)(ub >> 16);               // trunc
    float lof = w - __uint_as_float(ub & 0xFFFF0000u);
    unsigned short lo = bf16_rne(lof);
    wf[((cg * 2 + ks) * 2 + 0) * 512 + slot * 8 + e] = hi;
    wf[((cg * 2 + ks) * 2 + 1) * 512 + slot * 8 + e] = lo;
}

// One 64-thread (1-wave) block, NB consecutive batches, zero main-loop
// barriers (R7). NEW: software-pipelined tile loop — per iteration:
//   ds_read A(t) -> issue muon loads(t+1) -> MFMA(t) [pipe covers load
//   latency] -> L1+split+write(t+1) [VALU, loads already landed] -> fold(t).
// Single LDS buffer is safe: same-wave DS ops issue in program order, so
// writes(t+1) follow reads(t). Split uses v_cvt_pk_bf16_f32 (1 instr per
// f32 pair vs ~6 scalar ops/elem in R7).
__global__ __launch_bounds__(64, 2) void critic_kernel(
    const float* __restrict__ muons,   // [M,3]
    const float* __restrict__ conds,   // [B,4]
    const int*   __restrict__ seg,     // [B+1]
    const float* __restrict__ w1,      // [7,64]
    const float* __restrict__ b1,      // [64]
    const unsigned short* __restrict__ w2frag,  // packed by prep_w2_kernel
    const float* __restrict__ b2,      // [128]
    const float* __restrict__ w3,      // [132,128]
    const float* __restrict__ b3,      // [128]
    const float* __restrict__ w4,      // [128]
    const float* __restrict__ b4,      // [1]
    float* __restrict__ out,           // [B]
    float scale, int Btot)
{
    __shared__ __align__(16) float w1t[64 * 8];  // [k][i], i<7: w1[i][k], i==7: b1[k]
    __shared__ __align__(16) char  alds[2][4096]; // [p][row 32][k 64] bf16, swizzled
    __shared__ float din[132];

    const int tid = threadIdx.x;      // == lane
    const int l16 = tid & 15;
    const int lkg = tid >> 4;
    const int mslot = tid >> 1;       // muon slot 0..31
    const int half  = tid & 1;        // k-half

    // ---- stage w1(+b1) into LDS ----
    for (int idx = tid; idx < 512; idx += 64) {
        int k = idx >> 3, i = idx & 7;
        w1t[idx] = (i < 7) ? w1[i * 64 + k] : b1[k];
    }

    // ---- ALL 8 col-groups of w2 hi/lo into registers: 32 x dwordx4 ----
    short8 bhi[8][2], blo[8][2];
    {
        const short8* wf = (const short8*)w2frag;
        #pragma unroll
        for (int cg = 0; cg < 8; ++cg) {
            #pragma unroll
            for (int ks = 0; ks < 2; ++ks) {
                bhi[cg][ks] = wf[((cg * 2 + ks) * 2 + 0) * 64 + tid];
                blo[cg][ks] = wf[((cg * 2 + ks) * 2 + 1) * 64 + tid];
            }
        }
    }
    __syncthreads();

    // ---- tile-invariant LDS addresses ----
    unsigned wa[4];
    {
        const unsigned wsw = (unsigned)((mslot & 7) << 4);
        #pragma unroll
        for (int g = 0; g < 4; ++g)
            wa[g] = ((unsigned)(mslot * 128 + half * 64 + g * 16)) ^ wsw;
    }
    unsigned rb[2];
    #pragma unroll
    for (int rt = 0; rt < 2; ++rt) {
        const int row = rt * 16 + l16;
        rb[rt] = ((unsigned)(row * 128 + lkg * 16)) ^ ((unsigned)((row & 7) << 4));
    }
    const float* w1h = w1t + half * 256;   // this thread's 32 k-rows of [8]

    for (int bi = 0; bi < NB; ++bi) {
        const int b = blockIdx.x * NB + bi;
        if (b >= Btot) break;

        const float c0 = conds[b * 4 + 0];
        const float c1 = conds[b * 4 + 1];
        const float c2 = conds[b * 4 + 2];
        const float c3 = conds[b * 4 + 3];
        const int start = seg[b];
        const int end   = seg[b + 1];
        const int nrows = end - start;

        // layer-1 for one muon (x0,x1,x2) -> split -> swizzled LDS write
        auto l1_write = [&](float x0, float x1, float x2) {
            #pragma unroll
            for (int g = 0; g < 4; ++g) {
                float hv[8];
                #pragma unroll
                for (int u = 0; u < 8; ++u) {
                    const float* wk = &w1h[(g * 8 + u) * 8];
                    float s = wk[7];
                    s = fmaf(x0, wk[0], s);
                    s = fmaf(x1, wk[1], s);
                    s = fmaf(x2, wk[2], s);
                    s = fmaf(c0, wk[3], s);
                    s = fmaf(c1, wk[4], s);
                    s = fmaf(c2, wk[5], s);
                    s = fmaf(c3, wk[6], s);
                    hv[u] = fmaxf(s, 0.2f * s);
                }
                unsigned hw0, hw1, hw2, hw3, lw0, lw1, lw2, lw3;
                {
                    unsigned h;
                    h = cvt_pk_bf16(hv[0], hv[1]); hw0 = h;
                    lw0 = cvt_pk_bf16(hv[0] - __uint_as_float(h << 16),
                                      hv[1] - __uint_as_float(h & 0xFFFF0000u));
                    h = cvt_pk_bf16(hv[2], hv[3]); hw1 = h;
                    lw1 = cvt_pk_bf16(hv[2] - __uint_as_float(h << 16),
                                      hv[3] - __uint_as_float(h & 0xFFFF0000u));
                    h = cvt_pk_bf16(hv[4], hv[5]); hw2 = h;
                    lw2 = cvt_pk_bf16(hv[4] - __uint_as_float(h << 16),
                                      hv[5] - __uint_as_float(h & 0xFFFF0000u));
                    h = cvt_pk_bf16(hv[6], hv[7]); hw3 = h;
                    lw3 = cvt_pk_bf16(hv[6] - __uint_as_float(h << 16),
                                      hv[7] - __uint_as_float(h & 0xFFFF0000u));
                }
                *(uint4*)(&alds[0][wa[g]]) = make_uint4(hw0, hw1, hw2, hw3);
                *(uint4*)(&alds[1][wa[g]]) = make_uint4(lw0, lw1, lw2, lw3);
            }
        };

        float gmax[8];
        #pragma unroll
        for (int cg = 0; cg < 8; ++cg) gmax[cg] = NEGF;

        if (nrows > 0) {
            const int ntiles = (nrows + 31) >> 5;

            // prologue: tile 0 -> LDS (unhidden load, once per batch)
            if (mslot < min(32, nrows)) {
                const int gm = start + mslot;
                l1_write(muons[gm * 3 + 0], muons[gm * 3 + 1], muons[gm * 3 + 2]);
            }

            for (int t = 0; t < ntiles; ++t) {
                const int rem = nrows - t * 32;

                // ---- ds_read A-fragments of tile t ----
                short8 ah0[2], ah1[2], al0[2], al1[2];
                #pragma unroll
                for (int rt = 0; rt < 2; ++rt) {
                    ah0[rt] = *(const short8*)(&alds[0][rb[rt]]);
                    ah1[rt] = *(const short8*)(&alds[0][rb[rt] ^ 64u]);
                    al0[rt] = *(const short8*)(&alds[1][rb[rt]]);
                    al1[rt] = *(const short8*)(&alds[1][rb[rt] ^ 64u]);
                }

                // ---- issue muon loads for tile t+1 (land under MFMA) ----
                const bool hasN = rem > 32;
                bool mv = false;
                float xn0 = 0.f, xn1 = 0.f, xn2 = 0.f;
                if (hasN) {
                    mv = mslot < min(32, rem - 32);
                    if (mv) {
                        const int gm = start + t * 32 + 32 + mslot;
                        xn0 = muons[gm * 3 + 0];
                        xn1 = muons[gm * 3 + 1];
                        xn2 = muons[gm * 3 + 2];
                    }
                }

                // ---- MFMA: 3-pass split-bf16, both row-tiles ----
                f32x4 acc0[8], acc1[8];
                #pragma unroll
                for (int cg = 0; cg < 8; ++cg) {
                    f32x4 c = (f32x4){0.f, 0.f, 0.f, 0.f};
                    c = __builtin_amdgcn_mfma_f32_16x16x32_bf16(ah0[0], bhi[cg][0], c, 0, 0, 0);
                    c = __builtin_amdgcn_mfma_f32_16x16x32_bf16(ah1[0], bhi[cg][1], c, 0, 0, 0);
                    c = __builtin_amdgcn_mfma_f32_16x16x32_bf16(al0[0], bhi[cg][0], c, 0, 0, 0);
                    c = __builtin_amdgcn_mfma_f32_16x16x32_bf16(al1[0], bhi[cg][1], c, 0, 0, 0);
                    c = __builtin_amdgcn_mfma_f32_16x16x32_bf16(ah0[0], blo[cg][0], c, 0, 0, 0);
                    c = __builtin_amdgcn_mfma_f32_16x16x32_bf16(ah1[0], blo[cg][1], c, 0, 0, 0);
                    acc0[cg] = c;
                }
                #pragma unroll
                for (int cg = 0; cg < 8; ++cg) {
                    f32x4 c = (f32x4){0.f, 0.f, 0.f, 0.f};
                    c = __builtin_amdgcn_mfma_f32_16x16x32_bf16(ah0[1], bhi[cg][0], c, 0, 0, 0);
                    c = __builtin_amdgcn_mfma_f32_16x16x32_bf16(ah1[1], bhi[cg][1], c, 0, 0, 0);
                    c = __builtin_amdgcn_mfma_f32_16x16x32_bf16(al0[1], bhi[cg][0], c, 0, 0, 0);
                    c = __builtin_amdgcn_mfma_f32_16x16x32_bf16(al1[1], bhi[cg][1], c, 0, 0, 0);
                    c = __builtin_amdgcn_mfma_f32_16x16x32_bf16(ah0[1], blo[cg][0], c, 0, 0, 0);
                    c = __builtin_amdgcn_mfma_f32_16x16x32_bf16(ah1[1], blo[cg][1], c, 0, 0, 0);
                    acc1[cg] = c;
                }

                // ---- layer-1 for tile t+1 (VALU; overlaps MFMA pipe) ----
                if (mv) l1_write(xn0, xn1, xn2);

                // ---- fold segment max of tile t ----
                const int cnt = min(32, rem);
                if (cnt == 32) {
                    #pragma unroll
                    for (int cg = 0; cg < 8; ++cg)
                        #pragma unroll
                        for (int j = 0; j < 4; ++j)
                            gmax[cg] = fmaxf(gmax[cg],
                                             fmaxf(acc0[cg][j], acc1[cg][j]));
                } else {
                    #pragma unroll
                    for (int cg = 0; cg < 8; ++cg)
                        #pragma unroll
                        for (int j = 0; j < 4; ++j) {
                            const int r0 = lkg * 4 + j;
                            const int r1 = 16 + lkg * 4 + j;
                            const float v0 = (r0 < cnt) ? acc0[cg][j] : NEGF;
                            const float v1 = (r1 < cnt) ? acc1[cg][j] : NEGF;
                            gmax[cg] = fmaxf(gmax[cg], fmaxf(v0, v1));
                        }
                }
            }
        }

        // ---- cross-lane max over row-groups (lkg), then din ----
        #pragma unroll
        for (int cg = 0; cg < 8; ++cg) {
            float v = gmax[cg];
            v = fmaxf(v, __shfl_xor(v, 16, 64));
            v = fmaxf(v, __shfl_xor(v, 32, 64));
            if (tid < 16) {
                const int col = cg * 16 + tid;
                const float biased = v + b2[col];
                const float actv = fmaxf(biased, 0.2f * biased);  // deferred leaky
                din[col] = (nrows > 0) ? actv : NEGF;             // empty-seg guard
            }
        }
        if (tid < 4) din[128 + tid] = conds[b * 4 + tid];
        // same-wave LDS ordering: no barrier needed

        // ---- decision net: 2 output columns per thread ----
        float g0 = b3[tid];
        float g1 = b3[64 + tid];
        #pragma unroll 4
        for (int i = 0; i < 132; ++i) {
            const float d = din[i];
            g0 = fmaf(d, w3[i * 128 + tid], g0);
            g1 = fmaf(d, w3[i * 128 + 64 + tid], g1);
        }
        g0 = fmaxf(g0, 0.2f * g0);
        g1 = fmaxf(g1, 0.2f * g1);
        float part = g0 * w4[tid] + g1 * w4[64 + tid];
        #pragma unroll
        for (int s = 1; s < 64; s <<= 1)
            part += __shfl_xor(part, s, 64);
        if (tid == 0) {
            float sc = (part + b4[0]) * scale;
            out[b] = fminf(fmaxf(sc, -1000.0f), 1000.0f);
        }
    }
}

extern "C" void kernel_launch(void* const* d_in, const int* in_sizes, int n_in,
                              void* d_out, int out_size, void* d_ws, size_t ws_size,
                              hipStream_t stream) {
    const float* muons = (const float*)d_in[0];
    const int*   bidx  = (const int*)d_in[1];
    const float* conds = (const float*)d_in[2];
    // d_in[3] = batch_size scalar (derive B from conditions instead)
    const float* w1 = (const float*)d_in[4];
    const float* b1 = (const float*)d_in[5];
    const float* w2 = (const float*)d_in[6];
    const float* b2 = (const float*)d_in[7];
    const float* w3 = (const float*)d_in[8];
    const float* b3 = (const float*)d_in[9];
    const float* w4 = (const float*)d_in[10];
    const float* b4 = (const float*)d_in[11];

    const int M = in_sizes[0] / 3;
    const int B = in_sizes[2] / 4;
    int* seg = (int*)d_ws;                                   // (B+1) ints
    const size_t off = (((size_t)(B + 1)) * 4 + 255) & ~(size_t)255;
    unsigned short* w2frag = (unsigned short*)((char*)d_ws + off);  // 32 KB
    const float scale = 1.0f / fmaxf(1.0f, sqrtf((float)B));

    seg_bounds_kernel<<<(M + 255) / 256, 256, 0, stream>>>(bidx, M, B, seg);
    prep_w2_kernel<<<32, 256, 0, stream>>>(w2, w2frag);
    const int nblk = (B + NB - 1) / NB;
    critic_kernel<<<nblk, 64, 0, stream>>>(muons, conds, seg,
                                           w1, b1, w2frag, b2, w3, b3, w4, b4,
                                           (float*)d_out, scale, B);
}

// Round 9
// 262.792 us; speedup vs baseline: 1.0739x; 1.0739x over previous
//
#include <hip/hip_runtime.h>
#include <math.h>

#define NEGF (-1.0e9f)
#define NB 4   // batches per block

typedef __attribute__((ext_vector_type(8))) short short8;
typedef __attribute__((ext_vector_type(4))) float f32x4;

static __device__ __forceinline__ unsigned short bf16_rne(float f) {
    unsigned int u = __float_as_uint(f);
    u += 0x7FFFu + ((u >> 16) & 1u);
    return (unsigned short)(u >> 16);
}

// packed 2x f32 -> 2x bf16 (RNE), D[15:0]=cvt(S0), D[31:16]=cvt(S1)
static __device__ __forceinline__ unsigned cvt_pk_bf16(float a, float b) {
    unsigned r;
    asm("v_cvt_pk_bf16_f32 %0, %1, %2" : "=v"(r) : "v"(a), "v"(b));
    return r;
}

// Kernel A: segment boundaries from sorted batch_index.
__global__ void seg_bounds_kernel(const int* __restrict__ bi, int M, int B,
                                  int* __restrict__ seg) {
    int m = blockIdx.x * blockDim.x + threadIdx.x;
    if (m >= M) return;
    int cur = bi[m];
    if (m == 0) {
        for (int b = 0; b <= cur; ++b) seg[b] = 0;
    } else {
        int prev = bi[m - 1];
        for (int b = prev + 1; b <= cur; ++b) seg[b] = m;
    }
    if (m == M - 1) {
        for (int b = cur + 1; b <= B; ++b) seg[b] = M;
    }
}

// Kernel P: split w2 [64 k][128 col] into hi/lo bf16 in per-lane MFMA
// B-fragment order. ushort layout: [cg 8][ks 2][p 2][slot 64][e 8],
// slot = kg*16+lane16, value = bf16split_p(w2[ks*32+kg*8+e][cg*16+lane16]).
__global__ void prep_w2_kernel(const float* __restrict__ w2,
                               unsigned short* __restrict__ wf) {
    int t = blockIdx.x * blockDim.x + threadIdx.x;   // 0..8191
    if (t >= 8192) return;
    int e = t & 7, slot = (t >> 3) & 63, ks = (t >> 9) & 1, cg = t >> 10;
    int lane16 = slot & 15, kg = slot >> 4;
    int k = ks * 32 + kg * 8 + e;
    int col = cg * 16 + lane16;
    float w = w2[k * 128 + col];
    unsigned ub = __float_as_uint(w);
    unsigned short hi = (unsigned short)(ub >> 16);               // trunc
    float lof = w - __uint_as_float(ub & 0xFFFF0000u);
    unsigned short lo = bf16_rne(lof);
    wf[((cg * 2 + ks) * 2 + 0) * 512 + slot * 8 + e] = hi;
    wf[((cg * 2 + ks) * 2 + 1) * 512 + slot * 8 + e] = lo;
}

// 128-thread (2-wave) block, NB consecutive batches.
// R8 post-mortem: 2 waves/SIMD (224 unified regs) couldn't cover stalls ->
// 60% dual-idle. This round: (a) wave owns only 4 col-groups (B-frags 64
// VGPR not 128) -> __launch_bounds__(128,3) targets 3 waves/SIMD;
// (b) L1 uses per-batch packed wpk[k]={w1x0,w1x1,w1x2,beff} where
// beff=b1+c.w1[3:7] is batch-constant: 1 ds_read_b128 + 3 FMA per output
// (was 2 reads + 7 FMA); (c) s_setprio(1) around MFMA clusters (T5).
// A-tile shared across the 2 waves via LDS, 2 barriers/tile — covered by
// ~6 resident blocks at mixed phases (unlike R6's 1.75 waves/SIMD).
__global__ __launch_bounds__(128, 3) void critic_kernel(
    const float* __restrict__ muons,   // [M,3]
    const float* __restrict__ conds,   // [B,4]
    const int*   __restrict__ seg,     // [B+1]
    const float* __restrict__ w1,      // [7,64]
    const float* __restrict__ b1,      // [64]
    const unsigned short* __restrict__ w2frag,  // packed by prep_w2_kernel
    const float* __restrict__ b2,      // [128]
    const float* __restrict__ w3,      // [132,128]
    const float* __restrict__ b3,      // [128]
    const float* __restrict__ w4,      // [128]
    const float* __restrict__ b4,      // [1]
    float* __restrict__ out,           // [B]
    float scale, int Btot)
{
    __shared__ __align__(16) char  alds[2][4096]; // [p][row 32][k 64] bf16, swizzled
    __shared__ __align__(16) float wpk[64][4];    // [k]: {w1x0,w1x1,w1x2,beff}
    __shared__ float din[132];
    __shared__ float red[2];

    const int tid  = threadIdx.x;
    const int wave = tid >> 6;
    const int lane = tid & 63;
    const int l16  = lane & 15;
    const int lkg  = lane >> 4;

    // ---- this wave's 4 col-groups of w2 hi/lo: 16 x dwordx4 = 64 VGPR ----
    short8 bhi[4][2], blo[4][2];
    {
        const short8* wf = (const short8*)w2frag;
        #pragma unroll
        for (int c = 0; c < 4; ++c) {
            const int cg = wave * 4 + c;
            #pragma unroll
            for (int ks = 0; ks < 2; ++ks) {
                bhi[c][ks] = wf[((cg * 2 + ks) * 2 + 0) * 64 + lane];
                blo[c][ks] = wf[((cg * 2 + ks) * 2 + 1) * 64 + lane];
            }
        }
    }

    // ---- phase-A geometry: 4 threads/muon, 16 k-outputs each ----
    const int arow = wave * 16 + (lane >> 2);   // muon row in tile, 0..31
    const int ko   = (lane & 3) * 16;           // k-offset 0/16/32/48
    const unsigned aswz  = (unsigned)((arow & 7) << 4);
    const unsigned wadr0 = ((unsigned)(arow * 128 + ko * 2)) ^ aswz;
    const unsigned wadr1 = ((unsigned)(arow * 128 + ko * 2 + 16)) ^ aswz;

    // ---- phase-B read addresses ----
    unsigned rb[2];
    #pragma unroll
    for (int rt = 0; rt < 2; ++rt) {
        const int row = rt * 16 + l16;
        rb[rt] = ((unsigned)(row * 128 + lkg * 16)) ^ ((unsigned)((row & 7) << 4));
    }

    // L1 for one muon -> split hi/lo -> swizzled LDS write (16 outputs)
    auto l1_write = [&](float x0, float x1, float x2) {
        float hv[16];
        #pragma unroll
        for (int i = 0; i < 16; ++i) {
            const f32x4 wr = *(const f32x4*)&wpk[ko + i][0];
            float s = wr[3];
            s = fmaf(x0, wr[0], s);
            s = fmaf(x1, wr[1], s);
            s = fmaf(x2, wr[2], s);
            hv[i] = fmaxf(s, 0.2f * s);
        }
        unsigned hw[8], lw[8];
        #pragma unroll
        for (int j = 0; j < 8; ++j) {
            const unsigned h = cvt_pk_bf16(hv[2 * j], hv[2 * j + 1]);
            hw[j] = h;
            lw[j] = cvt_pk_bf16(hv[2 * j]     - __uint_as_float(h << 16),
                                hv[2 * j + 1] - __uint_as_float(h & 0xFFFF0000u));
        }
        *(uint4*)(&alds[0][wadr0]) = make_uint4(hw[0], hw[1], hw[2], hw[3]);
        *(uint4*)(&alds[0][wadr1]) = make_uint4(hw[4], hw[5], hw[6], hw[7]);
        *(uint4*)(&alds[1][wadr0]) = make_uint4(lw[0], lw[1], lw[2], lw[3]);
        *(uint4*)(&alds[1][wadr1]) = make_uint4(lw[4], lw[5], lw[6], lw[7]);
    };

    for (int bi = 0; bi < NB; ++bi) {
        const int b = blockIdx.x * NB + bi;
        if (b >= Btot) break;

        const float c0 = conds[b * 4 + 0];
        const float c1 = conds[b * 4 + 1];
        const float c2 = conds[b * 4 + 2];
        const float c3 = conds[b * 4 + 3];
        const int start = seg[b];
        const int end   = seg[b + 1];
        const int nrows = end - start;

        // ---- per-batch packed L1 weights: {w1x, beff} ----
        if (tid < 64) {
            float e = b1[tid];
            e = fmaf(c0, w1[3 * 64 + tid], e);
            e = fmaf(c1, w1[4 * 64 + tid], e);
            e = fmaf(c2, w1[5 * 64 + tid], e);
            e = fmaf(c3, w1[6 * 64 + tid], e);
            wpk[tid][0] = w1[0 * 64 + tid];
            wpk[tid][1] = w1[1 * 64 + tid];
            wpk[tid][2] = w1[2 * 64 + tid];
            wpk[tid][3] = e;
        }
        __syncthreads();   // wpk ready (also fences prev batch's din/red)

        float gmax[4];
        #pragma unroll
        for (int c = 0; c < 4; ++c) gmax[c] = NEGF;

        if (nrows > 0) {
            const int ntiles = (nrows + 31) >> 5;

            // prologue: tile 0 (unhidden load, once per batch)
            if (arow < min(32, nrows)) {
                const int gm = start + arow;
                l1_write(muons[gm * 3 + 0], muons[gm * 3 + 1], muons[gm * 3 + 2]);
            }

            for (int t = 0; t < ntiles; ++t) {
                const int rem = nrows - t * 32;
                const int cnt = min(32, rem);
                __syncthreads();   // A(t) visible to both waves

                // prefetch muons for t+1 (land under MFMA)
                float xn0 = 0.f, xn1 = 0.f, xn2 = 0.f;
                bool mv = false;
                if (rem > 32) {
                    mv = arow < min(32, rem - 32);
                    if (mv) {
                        const int gm = start + t * 32 + 32 + arow;
                        xn0 = muons[gm * 3 + 0];
                        xn1 = muons[gm * 3 + 1];
                        xn2 = muons[gm * 3 + 2];
                    }
                }

                // phase B: per row-tile: read A-frags, 24 MFMA, fold
                #pragma unroll
                for (int rt = 0; rt < 2; ++rt) {
                    const short8 ah0 = *(const short8*)(&alds[0][rb[rt]]);
                    const short8 ah1 = *(const short8*)(&alds[0][rb[rt] ^ 64u]);
                    const short8 al0 = *(const short8*)(&alds[1][rb[rt]]);
                    const short8 al1 = *(const short8*)(&alds[1][rb[rt] ^ 64u]);

                    f32x4 acc[4];
                    __builtin_amdgcn_s_setprio(1);
                    #pragma unroll
                    for (int c = 0; c < 4; ++c) {
                        f32x4 a = (f32x4){0.f, 0.f, 0.f, 0.f};
                        a = __builtin_amdgcn_mfma_f32_16x16x32_bf16(ah0, bhi[c][0], a, 0, 0, 0);
                        a = __builtin_amdgcn_mfma_f32_16x16x32_bf16(ah1, bhi[c][1], a, 0, 0, 0);
                        a = __builtin_amdgcn_mfma_f32_16x16x32_bf16(al0, bhi[c][0], a, 0, 0, 0);
                        a = __builtin_amdgcn_mfma_f32_16x16x32_bf16(al1, bhi[c][1], a, 0, 0, 0);
                        a = __builtin_amdgcn_mfma_f32_16x16x32_bf16(ah0, blo[c][0], a, 0, 0, 0);
                        a = __builtin_amdgcn_mfma_f32_16x16x32_bf16(ah1, blo[c][1], a, 0, 0, 0);
                        acc[c] = a;
                    }
                    __builtin_amdgcn_s_setprio(0);

                    #pragma unroll
                    for (int c = 0; c < 4; ++c)
                        #pragma unroll
                        for (int j = 0; j < 4; ++j) {
                            const int r = rt * 16 + lkg * 4 + j;
                            gmax[c] = fmaxf(gmax[c], (r < cnt) ? acc[c][j] : NEGF);
                        }
                }
                __syncthreads();   // reads done; safe to overwrite A
                if (mv) l1_write(xn0, xn1, xn2);
            }
        }

        // ---- din: wave-local columns (wave w owns cols w*64..+63) ----
        #pragma unroll
        for (int c = 0; c < 4; ++c) {
            float v = gmax[c];
            v = fmaxf(v, __shfl_xor(v, 16, 64));
            v = fmaxf(v, __shfl_xor(v, 32, 64));
            if (lane < 16) {
                const int col = wave * 64 + c * 16 + lane;
                const float biased = v + b2[col];
                const float actv = fmaxf(biased, 0.2f * biased);  // deferred leaky
                din[col] = (nrows > 0) ? actv : NEGF;             // empty-seg guard
            }
        }
        if (tid < 4) din[128 + tid] = conds[b * 4 + tid];
        __syncthreads();   // din complete

        // ---- decision net: one output column per thread ----
        float g = b3[tid];
        #pragma unroll 4
        for (int i = 0; i < 132; ++i)
            g = fmaf(din[i], w3[i * 128 + tid], g);
        g = fmaxf(g, 0.2f * g);
        float part = g * w4[tid];
        #pragma unroll
        for (int s = 1; s < 64; s <<= 1)
            part += __shfl_xor(part, s, 64);
        if (lane == 0) red[wave] = part;
        __syncthreads();
        if (tid == 0) {
            float sc = (red[0] + red[1] + b4[0]) * scale;
            out[b] = fminf(fmaxf(sc, -1000.0f), 1000.0f);
        }
    }
}

extern "C" void kernel_launch(void* const* d_in, const int* in_sizes, int n_in,
                              void* d_out, int out_size, void* d_ws, size_t ws_size,
                              hipStream_t stream) {
    const float* muons = (const float*)d_in[0];
    const int*   bidx  = (const int*)d_in[1];
    const float* conds = (const float*)d_in[2];
    // d_in[3] = batch_size scalar (derive B from conditions instead)
    const float* w1 = (const float*)d_in[4];
    const float* b1 = (const float*)d_in[5];
    const float* w2 = (const float*)d_in[6];
    const float* b2 = (const float*)d_in[7];
    const float* w3 = (const float*)d_in[8];
    const float* b3 = (const float*)d_in[9];
    const float* w4 = (const float*)d_in[10];
    const float* b4 = (const float*)d_in[11];

    const int M = in_sizes[0] / 3;
    const int B = in_sizes[2] / 4;
    int* seg = (int*)d_ws;                                   // (B+1) ints
    const size_t off = (((size_t)(B + 1)) * 4 + 255) & ~(size_t)255;
    unsigned short* w2frag = (unsigned short*)((char*)d_ws + off);  // 32 KB
    const float scale = 1.0f / fmaxf(1.0f, sqrtf((float)B));

    seg_bounds_kernel<<<(M + 255) / 256, 256, 0, stream>>>(bidx, M, B, seg);
    prep_w2_kernel<<<32, 256, 0, stream>>>(w2, w2frag);
    const int nblk = (B + NB - 1) / NB;
    critic_kernel<<<nblk, 128, 0, stream>>>(muons, conds, seg,
                                            w1, b1, w2frag, b2, w3, b3, w4, b4,
                                            (float*)d_out, scale, B);
}